// Round 1
// baseline (929.977 us; speedup 1.0000x reference)
//
#include <hip/hip_runtime.h>

#define B_   16
#define NBOX 36

// ---------------- ROI align ----------------
// grid: B_*128 blocks (b, c-chunk of 8), 256 threads.
// Stages 8 full 32x32 feature maps in LDS (coalesced, reads lf exactly once),
// computes all 36 boxes x 9 output pixels for those channels.
__global__ void roi_kernel(const float* __restrict__ lf,     // (16,1024,32,32)
                           const float* __restrict__ boxes,  // (16,36,4)
                           float* __restrict__ roi)          // (16,36,9,1024)
{
    __shared__ float F[8][1025];
    __shared__ int   s_yl[NBOX*6], s_yh[NBOX*6], s_xl[NBOX*6], s_xh[NBOX*6];
    __shared__ float s_ly[NBOX*6], s_lx[NBOX*6], s_vy[NBOX*6], s_vx[NBOX*6];

    const int b   = blockIdx.x >> 7;
    const int c0  = (blockIdx.x & 127) << 3;
    const int tid = threadIdx.x;

    for (int idx = tid; idx < 8 * 1024; idx += 256) {
        int c = idx >> 10, pix = idx & 1023;
        F[c][pix] = lf[((size_t)((b << 10) + c0 + c) << 10) + pix];
    }
    if (tid < NBOX * 6) {
        int n = tid / 6, j = tid % 6;
        const float* bx = boxes + ((b * NBOX + n) << 2);
        float x1 = bx[0] * 32.f, y1 = bx[1] * 32.f;
        float x2 = bx[2] * 32.f, y2 = bx[3] * 32.f;
        float rw = fmaxf(x2 - x1, 1.f), rh = fmaxf(y2 - y1, 1.f);
        float off = ((float)j + 0.5f) * (1.0f / 6.0f);
        float ys = y1 + rh * off;
        float xs = x1 + rw * off;
        {   // y side
            float v = (ys >= -1.f && ys <= 32.f) ? 1.f : 0.f;
            float y = fmaxf(ys, 0.f);
            int fy = (int)floorf(y);
            bool t = (fy >= 31);
            s_yl[tid] = (t ? 31 : fy) * 32;
            s_yh[tid] = (t ? 31 : fy + 1) * 32;
            s_ly[tid] = t ? 0.f : (y - (float)fy);
            s_vy[tid] = v;
        }
        {   // x side
            float v = (xs >= -1.f && xs <= 32.f) ? 1.f : 0.f;
            float x = fmaxf(xs, 0.f);
            int fx = (int)floorf(x);
            bool t = (fx >= 31);
            s_xl[tid] = t ? 31 : fx;
            s_xh[tid] = t ? 31 : fx + 1;
            s_lx[tid] = t ? 0.f : (x - (float)fx);
            s_vx[tid] = v;
        }
    }
    __syncthreads();

    // 324 (n,p) pairs x 8 channels = 2592 items
    for (int it = tid; it < 324 * 8; it += 256) {
        int c  = it & 7;
        int np = it >> 3;
        int n = np / 9, p = np % 9;
        int py = p / 3, px = p % 3;
        float acc = 0.f;
        #pragma unroll
        for (int sy = 0; sy < 2; ++sy) {
            int iy = n * 6 + py * 2 + sy;
            float ly = s_ly[iy], hy = 1.f - ly, vy = s_vy[iy];
            int yl = s_yl[iy], yh = s_yh[iy];
            #pragma unroll
            for (int sx = 0; sx < 2; ++sx) {
                int ix = n * 6 + px * 2 + sx;
                float lx = s_lx[ix], hx = 1.f - lx;
                int xl = s_xl[ix], xh = s_xh[ix];
                float val = hy * (hx * F[c][yl + xl] + lx * F[c][yl + xh])
                          + ly * (hx * F[c][yh + xl] + lx * F[c][yh + xh]);
                acc += vy * s_vx[ix] * val;
            }
        }
        roi[(((size_t)(b * NBOX + n) * 9 + p) << 10) + c0 + c] = acc * 0.25f;
    }
}

// ---------------- init: pre-fill biases ----------------
// x_pre (16,36,5120) <- [bg | bl broadcast over 9 slots]; feats (16,36,512) <- bm
__global__ void init_kernel(const float* __restrict__ bg, const float* __restrict__ bl,
                            const float* __restrict__ bm,
                            float* __restrict__ x_pre, float* __restrict__ feats)
{
    int idx = blockIdx.x * 256 + threadIdx.x;
    const int XT = 16 * 36 * 5120;
    if (idx < XT) {
        int j = idx % 5120;
        int n = (idx / 5120) % 36;
        x_pre[idx] = (j < 512) ? bg[(n << 9) + j] : bl[(n << 9) + (j & 511)];
    } else {
        int i2 = idx - XT;
        if (i2 < 16 * 36 * 512) {
            int h = i2 & 511;
            int n = (i2 >> 9) % 36;
            feats[i2] = bm[(n << 9) + h];
        }
    }
}

// ---------------- xg: gf(16,1024) @ Wg[n](1024,512) ----------------
// grid (36, 8 h-chunks of 64, 2 k-splits of 512), 256 thr: h=tid&63, mg=tid>>6 (4 m each)
__global__ void xg_kernel(const float* __restrict__ gf, const float* __restrict__ Wg,
                          float* __restrict__ x_pre)
{
    const int n = blockIdx.x, hb = blockIdx.y << 6, kb = blockIdx.z << 9;
    const int tid = threadIdx.x;
    const int h = tid & 63, mg = tid >> 6;
    __shared__ float A[64][20];
    float acc[4] = {0.f, 0.f, 0.f, 0.f};
    const float* Wp = Wg + ((size_t)n << 19) + hb + h;
    for (int k0 = 0; k0 < 512; k0 += 64) {
        __syncthreads();
        for (int idx = tid; idx < 16 * 64; idx += 256) {
            int m = idx >> 6, k = idx & 63;
            A[k][m] = gf[(m << 10) + kb + k0 + k];
        }
        __syncthreads();
        #pragma unroll 8
        for (int k = 0; k < 64; ++k) {
            float w = Wp[(size_t)(kb + k0 + k) << 9];
            float4 a = *reinterpret_cast<const float4*>(&A[k][mg << 2]);
            acc[0] += a.x * w; acc[1] += a.y * w;
            acc[2] += a.z * w; acc[3] += a.w * w;
        }
    }
    #pragma unroll
    for (int i = 0; i < 4; ++i) {
        int m = (mg << 2) + i;
        atomicAdd(&x_pre[(size_t)(m * NBOX + n) * 5120 + hb + h], acc[i]);
    }
}

// ---------------- xl: roi rows(144,1024) @ Wl[n](1024,512) ----------------
// grid (36, 8 h-chunks of 64, 3 m-chunks of 48), 256 thr: h=tid&63, mg=tid>>6 (12 m each)
__global__ void xl_kernel(const float* __restrict__ roi, const float* __restrict__ Wl,
                          float* __restrict__ x_pre)
{
    const int n = blockIdx.x, hb = blockIdx.y << 6, mc = blockIdx.z * 48;
    const int tid = threadIdx.x;
    const int h = tid & 63, mg = tid >> 6;
    __shared__ float A[32][52];
    float acc[12];
    #pragma unroll
    for (int i = 0; i < 12; ++i) acc[i] = 0.f;
    const float* Wp = Wl + ((size_t)n << 19) + hb + h;
    for (int k0 = 0; k0 < 1024; k0 += 32) {
        __syncthreads();
        for (int idx = tid; idx < 48 * 32; idx += 256) {
            int r = idx >> 5, k = idx & 31;
            int R = mc + r;
            int bb = R / 9, p = R % 9;
            A[k][r] = roi[(((size_t)(bb * NBOX + n) * 9 + p) << 10) + k0 + k];
        }
        __syncthreads();
        #pragma unroll 8
        for (int k = 0; k < 32; ++k) {
            float w = Wp[(size_t)(k0 + k) << 9];
            float4 a0 = *reinterpret_cast<const float4*>(&A[k][mg * 12]);
            float4 a1 = *reinterpret_cast<const float4*>(&A[k][mg * 12 + 4]);
            float4 a2 = *reinterpret_cast<const float4*>(&A[k][mg * 12 + 8]);
            acc[0] += a0.x * w; acc[1]  += a0.y * w; acc[2]  += a0.z * w; acc[3]  += a0.w * w;
            acc[4] += a1.x * w; acc[5]  += a1.y * w; acc[6]  += a1.z * w; acc[7]  += a1.w * w;
            acc[8] += a2.x * w; acc[9]  += a2.y * w; acc[10] += a2.z * w; acc[11] += a2.w * w;
        }
    }
    #pragma unroll
    for (int i = 0; i < 12; ++i) {
        int R = mc + mg * 12 + i;
        int bb = R / 9, p = R % 9;
        size_t o = (size_t)(bb * NBOX + n) * 5120 + 512 + (p << 9) + hb + h;
        x_pre[o] += acc[i];  // disjoint ownership; bias pre-filled by init
    }
}

// ---------------- feats: relu(x)(16,5120) @ Wm[n](5120,512) ----------------
// grid (36, 8 h-chunks of 64, 4 k-splits of 1280), 256 thr: h=tid&63, mg=tid>>6 (4 m each)
__global__ void feats_kernel(const float* __restrict__ x_pre, const float* __restrict__ Wm,
                             float* __restrict__ feats)
{
    const int n = blockIdx.x, hb = blockIdx.y << 6, kb = blockIdx.z * 1280;
    const int tid = threadIdx.x;
    const int h = tid & 63, mg = tid >> 6;
    __shared__ float A[64][20];
    float acc[4] = {0.f, 0.f, 0.f, 0.f};
    const float* Wp = Wm + (size_t)n * 5120 * 512 + hb + h;
    for (int k0 = 0; k0 < 1280; k0 += 64) {
        __syncthreads();
        for (int idx = tid; idx < 16 * 64; idx += 256) {
            int m = idx >> 6, k = idx & 63;
            float v = x_pre[(size_t)(m * NBOX + n) * 5120 + kb + k0 + k];
            A[k][m] = fmaxf(v, 0.f);   // relu applied on load
        }
        __syncthreads();
        #pragma unroll 8
        for (int k = 0; k < 64; ++k) {
            float w = Wp[(size_t)(kb + k0 + k) << 9];
            float4 a = *reinterpret_cast<const float4*>(&A[k][mg << 2]);
            acc[0] += a.x * w; acc[1] += a.y * w;
            acc[2] += a.z * w; acc[3] += a.w * w;
        }
    }
    #pragma unroll
    for (int i = 0; i < 4; ++i) {
        int m = (mg << 2) + i;
        atomicAdd(&feats[(size_t)(m * NBOX + n) * 512 + hb + h], acc[i]);
    }
}

// ---------------- tail: loc + grp heads ----------------
// grid 576+192 blocks, 64 threads (1 wave)
__global__ void tail_kernel(const float* __restrict__ feats,
                            const float* __restrict__ Wloc, const float* __restrict__ bloc,
                            const float* __restrict__ Wgrp, const float* __restrict__ bgrp,
                            float* __restrict__ out)
{
    const int bid = blockIdx.x, lane = threadIdx.x;
    if (bid < 576) {
        int b = bid / 36, n = bid % 36;
        float acc[5] = {0.f, 0.f, 0.f, 0.f, 0.f};
        const float* f = feats + (size_t)(b * 36 + n) * 512;
        const float* W = Wloc + n * 2560;
        for (int k = lane; k < 512; k += 64) {
            float fv = f[k];
            #pragma unroll
            for (int l = 0; l < 5; ++l) acc[l] += fv * W[k * 5 + l];
        }
        #pragma unroll
        for (int l = 0; l < 5; ++l) {
            float v = acc[l];
            for (int off = 32; off; off >>= 1) v += __shfl_xor(v, off);
            if (lane == 0) out[b * 300 + n * 5 + l] = v + bloc[n * 5 + l];
        }
    } else {
        int bid2 = bid - 576;
        int b = bid2 / 12, g = bid2 % 12;
        float acc[10];
        #pragma unroll
        for (int l = 0; l < 10; ++l) acc[l] = 0.f;
        const float* f = feats + (size_t)(b * 36 + g * 3) * 512;  // 1536 contiguous
        const float* W = Wgrp + g * 15360;
        for (int k = lane; k < 1536; k += 64) {
            float fv = f[k];
            #pragma unroll
            for (int l = 0; l < 10; ++l) acc[l] += fv * W[k * 10 + l];
        }
        #pragma unroll
        for (int l = 0; l < 10; ++l) {
            float v = acc[l];
            for (int off = 32; off; off >>= 1) v += __shfl_xor(v, off);
            if (lane == 0) out[b * 300 + 180 + g * 10 + l] = v + bgrp[g * 10 + l];
        }
    }
}

extern "C" void kernel_launch(void* const* d_in, const int* in_sizes, int n_in,
                              void* d_out, int out_size, void* d_ws, size_t ws_size,
                              hipStream_t stream) {
    const float* lf   = (const float*)d_in[0];
    const float* gf   = (const float*)d_in[1];
    const float* bbox = (const float*)d_in[2];
    const float* Wg   = (const float*)d_in[3];
    const float* bg   = (const float*)d_in[4];
    const float* Wl   = (const float*)d_in[5];
    const float* bl   = (const float*)d_in[6];
    const float* Wm   = (const float*)d_in[7];
    const float* bm   = (const float*)d_in[8];
    const float* Wloc = (const float*)d_in[9];
    const float* bloc = (const float*)d_in[10];
    const float* Wgrp = (const float*)d_in[11];
    const float* bgrp = (const float*)d_in[12];
    float* out = (float*)d_out;

    float* roi   = (float*)d_ws;          // 16*36*9*1024   = 5,308,416 f32
    float* x_pre = roi + 5308416;         // 16*36*5120     = 2,949,120 f32
    float* feats = x_pre + 2949120;       // 16*36*512      =   294,912 f32
                                          // total ~34.2 MB of d_ws

    roi_kernel  <<<2048, 256, 0, stream>>>(lf, bbox, roi);
    init_kernel <<<12672, 256, 0, stream>>>(bg, bl, bm, x_pre, feats);
    xg_kernel   <<<dim3(36, 8, 2), 256, 0, stream>>>(gf, Wg, x_pre);
    xl_kernel   <<<dim3(36, 8, 3), 256, 0, stream>>>(roi, Wl, x_pre);
    feats_kernel<<<dim3(36, 8, 4), 256, 0, stream>>>(x_pre, Wm, feats);
    tail_kernel <<<768, 64, 0, stream>>>(feats, Wloc, bloc, Wgrp, bgrp, out);
}